// Round 2
// baseline (672.502 us; speedup 1.0000x reference)
//
#include <hip/hip_runtime.h>
#include <hip/hip_bf16.h>
#include <stdint.h>

// MultiHeadAttention: B=4, S=1024, D=1024, H=16, Dh=64
// d_out = [out (4M fp32)] ++ [attention raw logits (64M fp32)]

typedef __attribute__((ext_vector_type(8))) short v8s;   // 8 x bf16 bits
typedef __attribute__((ext_vector_type(4))) float v4f;

#define S_ 1024
#define MTOT 4096

__device__ __forceinline__ unsigned short f2b(float f) {
  union { float f; unsigned int u; } x; x.f = f;
  unsigned int u = x.u + 0x7fffu + ((x.u >> 16) & 1u);  // RNE
  return (unsigned short)(u >> 16);
}

// ---------- cast fp32 -> bf16, 8 elems/thread ----------
__global__ __launch_bounds__(256) void cast_bf16_k(const float* __restrict__ src,
                                                   unsigned short* __restrict__ dst) {
  int i = (blockIdx.x * 256 + threadIdx.x) * 8;
  v4f a = *(const v4f*)(src + i);
  v4f b = *(const v4f*)(src + i + 4);
  union { unsigned short u[8]; v8s v; } o;
  o.u[0] = f2b(a[0]); o.u[1] = f2b(a[1]); o.u[2] = f2b(a[2]); o.u[3] = f2b(a[3]);
  o.u[4] = f2b(b[0]); o.u[5] = f2b(b[1]); o.u[6] = f2b(b[2]); o.u[7] = f2b(b[3]);
  *(v8s*)(dst + i) = o.v;
}

// ---------- transpose + cast W[k][n] -> WT[n][k] bf16 ----------
__global__ __launch_bounds__(256) void transpose_cast_k(
    const float* __restrict__ W0, const float* __restrict__ W1,
    const float* __restrict__ W2, const float* __restrict__ W3,
    unsigned short* __restrict__ T0, unsigned short* __restrict__ T1,
    unsigned short* __restrict__ T2, unsigned short* __restrict__ T3) {
  const float* W = blockIdx.z == 0 ? W0 : blockIdx.z == 1 ? W1 : blockIdx.z == 2 ? W2 : W3;
  unsigned short* T = blockIdx.z == 0 ? T0 : blockIdx.z == 1 ? T1 : blockIdx.z == 2 ? T2 : T3;
  __shared__ float tile[32][33];
  int tx = threadIdx.x & 31, ty = threadIdx.x >> 5;
  int n0 = blockIdx.x * 32, k0 = blockIdx.y * 32;
#pragma unroll
  for (int i = 0; i < 4; i++)
    tile[ty + i * 8][tx] = W[(size_t)(k0 + ty + i * 8) * 1024 + n0 + tx];
  __syncthreads();
#pragma unroll
  for (int i = 0; i < 4; i++)
    T[(size_t)(n0 + ty + i * 8) * 1024 + k0 + tx] = f2b(tile[tx][ty + i * 8]);
}

// ---------- generic 128x128 bf16 GEMM, K=1024, B given transposed [n][k] ----------
// MODE 0: out = Qh bf16 [B,H,S,64]   MODE 1: out = Kh bf16 [B,H,S,64]
// MODE 2: out = Vt bf16 [B,H,64,S]   MODE 3: out = fp32 [4096][1024]
template <int MODE>
__global__ __launch_bounds__(256, 2) void gemm_k1024(
    const unsigned short* __restrict__ A, const unsigned short* __restrict__ Bt,
    const float* __restrict__ bias, void* __restrict__ Out) {
  __shared__ unsigned short As[128 * 64];
  __shared__ unsigned short Bs[128 * 64];
  const int t = threadIdx.x;
  const int wid = t >> 6, lane = t & 63;
  const int lrow = lane & 15, lquad = lane >> 4;
  const int m0 = blockIdx.x * 128, n0 = blockIdx.y * 128;
  const int wm = (wid & 1) * 64, wn = (wid >> 1) * 64;
  v4f zero = {0.f, 0.f, 0.f, 0.f};
  v4f acc[4][4];
#pragma unroll
  for (int i = 0; i < 4; i++)
#pragma unroll
    for (int j = 0; j < 4; j++) acc[i][j] = zero;

  for (int kt = 0; kt < 1024; kt += 64) {
    __syncthreads();
#pragma unroll
    for (int i = 0; i < 4; i++) {           // 128 rows x 8 col-groups = 1024 loads
      int c = t + i * 256;
      int r = c >> 3, col8 = (c & 7) * 8;
      *(v8s*)&As[r * 64 + col8] = *(const v8s*)&A[(size_t)(m0 + r) * 1024 + kt + col8];
      *(v8s*)&Bs[r * 64 + col8] = *(const v8s*)&Bt[(size_t)(n0 + r) * 1024 + kt + col8];
    }
    __syncthreads();
#pragma unroll
    for (int k32 = 0; k32 < 64; k32 += 32) {
      v8s af[4], bfv[4];
#pragma unroll
      for (int mi = 0; mi < 4; mi++)
        af[mi] = *(const v8s*)&As[(wm + mi * 16 + lrow) * 64 + k32 + lquad * 8];
#pragma unroll
      for (int ni = 0; ni < 4; ni++)
        bfv[ni] = *(const v8s*)&Bs[(wn + ni * 16 + lrow) * 64 + k32 + lquad * 8];
#pragma unroll
      for (int mi = 0; mi < 4; mi++)
#pragma unroll
        for (int ni = 0; ni < 4; ni++)
          acc[mi][ni] = __builtin_amdgcn_mfma_f32_16x16x32_bf16(af[mi], bfv[ni], acc[mi][ni], 0, 0, 0);
    }
  }
#pragma unroll
  for (int mi = 0; mi < 4; mi++) {
#pragma unroll
    for (int ni = 0; ni < 4; ni++) {
      int gn = n0 + wn + ni * 16 + lrow;
      float bv = bias[gn];
#pragma unroll
      for (int r = 0; r < 4; r++) {
        int gm = m0 + wm + mi * 16 + lquad * 4 + r;
        float val = acc[mi][ni][r] + bv;
        if (MODE == 0 || MODE == 1) {
          int b = gm >> 10, s = gm & 1023, h = gn >> 6, d = gn & 63;
          ((unsigned short*)Out)[(size_t)((b * 16 + h) * 1024 + s) * 64 + d] = f2b(val);
        } else if (MODE == 2) {
          int b = gm >> 10, s = gm & 1023, h = gn >> 6, d = gn & 63;
          ((unsigned short*)Out)[(size_t)((b * 16 + h) * 64 + d) * 1024 + s] = f2b(val);
        } else {
          ((float*)Out)[(size_t)gm * 1024 + gn] = val;
        }
      }
    }
  }
}

// ---------- logits: per (b,h) 1024x1024 = Qh[1024x64] @ Kh[1024x64]^T, raw fp32 ----------
__global__ __launch_bounds__(256, 2) void logits_gemm_k(
    const unsigned short* __restrict__ Qh, const unsigned short* __restrict__ Kh,
    float* __restrict__ attn) {
  __shared__ unsigned short As[128 * 64];
  __shared__ unsigned short Bs[128 * 64];
  const int z = blockIdx.z;
  const unsigned short* A = Qh + (size_t)z * S_ * 64;
  const unsigned short* Bm = Kh + (size_t)z * S_ * 64;
  const int t = threadIdx.x;
  const int wid = t >> 6, lane = t & 63;
  const int lrow = lane & 15, lquad = lane >> 4;
  const int m0 = blockIdx.x * 128, n0 = blockIdx.y * 128;
  const int wm = (wid & 1) * 64, wn = (wid >> 1) * 64;
  v4f zero = {0.f, 0.f, 0.f, 0.f};
  v4f acc[4][4];
#pragma unroll
  for (int i = 0; i < 4; i++)
#pragma unroll
    for (int j = 0; j < 4; j++) acc[i][j] = zero;

#pragma unroll
  for (int i = 0; i < 4; i++) {             // 128 rows x 8 col-groups = 1024 loads
    int c = t + i * 256;
    int r = c >> 3, col8 = (c & 7) * 8;
    *(v8s*)&As[r * 64 + col8] = *(const v8s*)&A[(size_t)(m0 + r) * 64 + col8];
    *(v8s*)&Bs[r * 64 + col8] = *(const v8s*)&Bm[(size_t)(n0 + r) * 64 + col8];
  }
  __syncthreads();
#pragma unroll
  for (int k32 = 0; k32 < 64; k32 += 32) {
    v8s af[4], bfv[4];
#pragma unroll
    for (int mi = 0; mi < 4; mi++)
      af[mi] = *(const v8s*)&As[(wm + mi * 16 + lrow) * 64 + k32 + lquad * 8];
#pragma unroll
    for (int ni = 0; ni < 4; ni++)
      bfv[ni] = *(const v8s*)&Bs[(wn + ni * 16 + lrow) * 64 + k32 + lquad * 8];
#pragma unroll
    for (int mi = 0; mi < 4; mi++)
#pragma unroll
      for (int ni = 0; ni < 4; ni++)
        acc[mi][ni] = __builtin_amdgcn_mfma_f32_16x16x32_bf16(af[mi], bfv[ni], acc[mi][ni], 0, 0, 0);
  }
  float* orow = attn + (size_t)z * S_ * S_;
#pragma unroll
  for (int mi = 0; mi < 4; mi++)
#pragma unroll
    for (int ni = 0; ni < 4; ni++) {
      int gn = n0 + wn + ni * 16 + lrow;
#pragma unroll
      for (int r = 0; r < 4; r++) {
        int gm = m0 + wm + mi * 16 + lquad * 4 + r;
        orow[(size_t)gm * 1024 + gn] = acc[mi][ni][r];
      }
    }
}

// ---------- softmax stats: per row (b,h,q): masked max + expsum over logits/8 ----------
__global__ __launch_bounds__(256) void softmax_stats_k(
    const float* __restrict__ attn, const float* __restrict__ q_mask,
    const float* __restrict__ k_mask, float* __restrict__ stats) {
  const int wid = threadIdx.x >> 6, lane = threadIdx.x & 63;
  const int r = blockIdx.x * 4 + wid;   // 65536 rows = b*16384 + h*1024 + q
  const int b = r >> 14, q = r & 1023;
  const float* row = attn + (size_t)r * 1024;
  const float* km = k_mask + b * 1024;
  float sv[16], kmv[16];
  float m = -1e30f;
#pragma unroll
  for (int i = 0; i < 16; i++) {
    int c = lane + i * 64;
    sv[i] = row[c] * 0.125f;
    kmv[i] = km[c];
    if (kmv[i] != 0.f) m = fmaxf(m, sv[i]);
  }
#pragma unroll
  for (int off = 32; off; off >>= 1) m = fmaxf(m, __shfl_xor(m, off));
  const bool any = (m > -1e29f);
  const float mm = any ? m : 0.f;
  float l = 0.f;
#pragma unroll
  for (int i = 0; i < 16; i++)
    if (kmv[i] != 0.f) l += __expf(sv[i] - mm);
#pragma unroll
  for (int off = 32; off; off >>= 1) l += __shfl_xor(l, off);
  if (lane == 0) {
    float recip = (any && q_mask[b * 1024 + q] != 0.f) ? (1.f / l) : 0.f;
    stats[r] = mm;
    stats[65536 + r] = recip;
  }
}

// ---------- context: per (b,h): C[1024x64] = P[1024x1024] @ Vt[64x1024]^T ----------
// A (probs) built on the fly from fp32 logits + stats + k_mask.
__global__ __launch_bounds__(256, 2) void context_gemm_k(
    const float* __restrict__ attn, const float* __restrict__ stats,
    const float* __restrict__ k_mask, const unsigned short* __restrict__ Vt,
    unsigned short* __restrict__ ctx) {
  __shared__ unsigned short As[256 * 64];  // 32 KB
  __shared__ unsigned short Bs[64 * 64];   // 8 KB
  const int z = blockIdx.z, b = z >> 4, h = z & 15;
  const int m0 = blockIdx.x * 256;
  const float* P = attn + (size_t)z * S_ * S_;
  const float* km = k_mask + b * 1024;
  const float* Ms = stats + (size_t)z * 1024;
  const float* Rs = stats + 65536 + (size_t)z * 1024;
  const int t = threadIdx.x;
  const int wid = t >> 6, lane = t & 63, lrow = lane & 15, lquad = lane >> 4;
  v4f zero = {0.f, 0.f, 0.f, 0.f};
  v4f acc[4][4];
#pragma unroll
  for (int i = 0; i < 4; i++)
#pragma unroll
    for (int j = 0; j < 4; j++) acc[i][j] = zero;

  for (int kt = 0; kt < 1024; kt += 64) {
    __syncthreads();
#pragma unroll
    for (int i = 0; i < 8; i++) {
      int c = t + i * 256;
      int r = c >> 3, col8 = (c & 7) * 8;
      int qq = m0 + r;
      float mR = Ms[qq], rR = Rs[qq];
      const v4f* s4 = (const v4f*)(P + (size_t)qq * 1024 + kt + col8);
      v4f x0 = s4[0], x1 = s4[1];
      union { unsigned short u[8]; v8s v; } o;
#pragma unroll
      for (int j = 0; j < 4; j++) {
        int kc = kt + col8 + j;
        o.u[j] = f2b(km[kc] != 0.f ? __expf(x0[j] * 0.125f - mR) * rR : 0.f);
      }
#pragma unroll
      for (int j = 0; j < 4; j++) {
        int kc = kt + col8 + 4 + j;
        o.u[4 + j] = f2b(km[kc] != 0.f ? __expf(x1[j] * 0.125f - mR) * rR : 0.f);
      }
      *(v8s*)&As[r * 64 + col8] = o.v;
    }
#pragma unroll
    for (int i = 0; i < 2; i++) {
      int c = t + i * 256;
      int r = c >> 3, col8 = (c & 7) * 8;
      *(v8s*)&Bs[r * 64 + col8] = *(const v8s*)&Vt[((size_t)z * 64 + r) * 1024 + kt + col8];
    }
    __syncthreads();
#pragma unroll
    for (int k32 = 0; k32 < 64; k32 += 32) {
      v8s af[4], bfv[4];
#pragma unroll
      for (int mi = 0; mi < 4; mi++)
        af[mi] = *(const v8s*)&As[(wid * 64 + mi * 16 + lrow) * 64 + k32 + lquad * 8];
#pragma unroll
      for (int ni = 0; ni < 4; ni++)
        bfv[ni] = *(const v8s*)&Bs[(ni * 16 + lrow) * 64 + k32 + lquad * 8];
#pragma unroll
      for (int mi = 0; mi < 4; mi++)
#pragma unroll
        for (int ni = 0; ni < 4; ni++)
          acc[mi][ni] = __builtin_amdgcn_mfma_f32_16x16x32_bf16(af[mi], bfv[ni], acc[mi][ni], 0, 0, 0);
    }
  }
#pragma unroll
  for (int mi = 0; mi < 4; mi++)
#pragma unroll
    for (int ni = 0; ni < 4; ni++) {
      int d = ni * 16 + lrow;
#pragma unroll
      for (int r = 0; r < 4; r++) {
        int s = m0 + wid * 64 + mi * 16 + lquad * 4 + r;
        ctx[(size_t)(b * 1024 + s) * 1024 + h * 64 + d] = f2b(acc[mi][ni][r]);
      }
    }
}

// ---------- residual + LayerNorm, one block per row ----------
__global__ __launch_bounds__(256) void resid_ln_k(
    const float* __restrict__ tmp, const float* __restrict__ resid,
    const float* __restrict__ gamma, const float* __restrict__ beta,
    float* __restrict__ out) {
  const int r = blockIdx.x, t = threadIdx.x;
  v4f x = *(const v4f*)(tmp + (size_t)r * 1024 + t * 4);
  v4f rv = *(const v4f*)(resid + (size_t)r * 1024 + t * 4);
  x = x + rv;
  float s = x[0] + x[1] + x[2] + x[3];
  float ss = x[0] * x[0] + x[1] * x[1] + x[2] * x[2] + x[3] * x[3];
#pragma unroll
  for (int off = 32; off; off >>= 1) { s += __shfl_xor(s, off); ss += __shfl_xor(ss, off); }
  __shared__ float red[8];
  const int wid = t >> 6, lane = t & 63;
  if (lane == 0) { red[wid] = s; red[4 + wid] = ss; }
  __syncthreads();
  s = red[0] + red[1] + red[2] + red[3];
  ss = red[4] + red[5] + red[6] + red[7];
  const float mu = s * (1.f / 1024.f);
  float var = ss * (1.f / 1024.f) - mu * mu;
  var = fmaxf(var, 0.f);
  const float rs = rsqrtf(var + 1e-5f);
  v4f g = *(const v4f*)(gamma + t * 4);
  v4f be = *(const v4f*)(beta + t * 4);
  v4f o = (x - mu) * rs * g + be;
  *(v4f*)(out + (size_t)r * 1024 + t * 4) = o;
}

extern "C" void kernel_launch(void* const* d_in, const int* in_sizes, int n_in,
                              void* d_out, int out_size, void* d_ws, size_t ws_size,
                              hipStream_t stream) {
  const float* q      = (const float*)d_in[0];
  const float* k      = (const float*)d_in[1];
  const float* v      = (const float*)d_in[2];
  const float* q_mask = (const float*)d_in[3];
  const float* k_mask = (const float*)d_in[4];
  const float* Wq = (const float*)d_in[5];
  const float* bq = (const float*)d_in[6];
  const float* Wk = (const float*)d_in[7];
  const float* bk = (const float*)d_in[8];
  const float* Wv = (const float*)d_in[9];
  const float* bv = (const float*)d_in[10];
  const float* Wf = (const float*)d_in[11];
  const float* bf = (const float*)d_in[12];
  const float* gamma = (const float*)d_in[13];
  const float* beta  = (const float*)d_in[14];

  float* out0 = (float*)d_out;
  float* attn = out0 + (size_t)MTOT * 1024;  // 64M fp32 raw logits

  char* w = (char*)d_ws;
  const size_t MB = (size_t)1 << 20;
  // [0,8): qb, later reused as ctx. [8,24): kb,vb, later reused as tmp fp32.
  unsigned short* qb  = (unsigned short*)(w + 0);
  unsigned short* kb  = (unsigned short*)(w + 8 * MB);
  unsigned short* vb  = (unsigned short*)(w + 16 * MB);
  unsigned short* WqT = (unsigned short*)(w + 24 * MB);
  unsigned short* WkT = (unsigned short*)(w + 26 * MB);
  unsigned short* WvT = (unsigned short*)(w + 28 * MB);
  unsigned short* WfT = (unsigned short*)(w + 30 * MB);
  unsigned short* Qh  = (unsigned short*)(w + 32 * MB);
  unsigned short* Kh  = (unsigned short*)(w + 40 * MB);
  unsigned short* Vt  = (unsigned short*)(w + 48 * MB);
  float* stats        = (float*)(w + 56 * MB);           // 512 KB
  unsigned short* ctx = (unsigned short*)(w + 0);        // reuse qb
  float* tmp          = (float*)(w + 8 * MB);            // reuse kb+vb (16 MB)

  cast_bf16_k<<<2048, 256, 0, stream>>>(q, qb);
  cast_bf16_k<<<2048, 256, 0, stream>>>(k, kb);
  cast_bf16_k<<<2048, 256, 0, stream>>>(v, vb);
  transpose_cast_k<<<dim3(32, 32, 4), 256, 0, stream>>>(Wq, Wk, Wv, Wf, WqT, WkT, WvT, WfT);
  gemm_k1024<0><<<dim3(32, 8), 256, 0, stream>>>(qb, WqT, bq, Qh);
  gemm_k1024<1><<<dim3(32, 8), 256, 0, stream>>>(kb, WkT, bk, Kh);
  gemm_k1024<2><<<dim3(32, 8), 256, 0, stream>>>(vb, WvT, bv, Vt);
  logits_gemm_k<<<dim3(8, 8, 64), 256, 0, stream>>>(Qh, Kh, attn);
  softmax_stats_k<<<16384, 256, 0, stream>>>(attn, q_mask, k_mask, stats);
  context_gemm_k<<<dim3(4, 1, 64), 256, 0, stream>>>(attn, stats, k_mask, Vt, ctx);
  gemm_k1024<3><<<dim3(32, 8), 256, 0, stream>>>(ctx, WfT, bf, tmp);
  resid_ln_k<<<4096, 256, 0, stream>>>(tmp, v, gamma, beta, out0);
}

// Round 3
// 640.013 us; speedup vs baseline: 1.0508x; 1.0508x over previous
//
#include <hip/hip_runtime.h>
#include <hip/hip_bf16.h>
#include <stdint.h>

// MultiHeadAttention: B=4, S=1024, D=1024, H=16, Dh=64
// d_out = [out (4M fp32)] ++ [attention raw logits (64M fp32)]

typedef __attribute__((ext_vector_type(8))) short v8s;   // 8 x bf16 bits
typedef __attribute__((ext_vector_type(4))) float v4f;

#define S_ 1024
#define MTOT 4096
#define LDA 72   // padded LDS row stride (bf16 elems): 144 B = 36 dwords -> conflict-free

__device__ __forceinline__ unsigned short f2b(float f) {
  union { float f; unsigned int u; } x; x.f = f;
  unsigned int u = x.u + 0x7fffu + ((x.u >> 16) & 1u);  // RNE
  return (unsigned short)(u >> 16);
}

// ---------- cast fp32 -> bf16 for q,k,v in one launch ----------
__global__ __launch_bounds__(256) void cast3_k(
    const float* __restrict__ q, const float* __restrict__ k, const float* __restrict__ v,
    unsigned short* __restrict__ qb, unsigned short* __restrict__ kb, unsigned short* __restrict__ vb) {
  const float* src = blockIdx.y == 0 ? q : blockIdx.y == 1 ? k : v;
  unsigned short* dst = blockIdx.y == 0 ? qb : blockIdx.y == 1 ? kb : vb;
  int i = (blockIdx.x * 256 + threadIdx.x) * 8;
  v4f a = *(const v4f*)(src + i);
  v4f b = *(const v4f*)(src + i + 4);
  union { unsigned short u[8]; v8s v; } o;
  o.u[0] = f2b(a[0]); o.u[1] = f2b(a[1]); o.u[2] = f2b(a[2]); o.u[3] = f2b(a[3]);
  o.u[4] = f2b(b[0]); o.u[5] = f2b(b[1]); o.u[6] = f2b(b[2]); o.u[7] = f2b(b[3]);
  *(v8s*)(dst + i) = o.v;
}

// ---------- transpose + cast W[k][n] -> WT[n][k] bf16 ----------
__global__ __launch_bounds__(256) void transpose_cast_k(
    const float* __restrict__ W0, const float* __restrict__ W1,
    const float* __restrict__ W2, const float* __restrict__ W3,
    unsigned short* __restrict__ T0, unsigned short* __restrict__ T1,
    unsigned short* __restrict__ T2, unsigned short* __restrict__ T3) {
  const float* W = blockIdx.z == 0 ? W0 : blockIdx.z == 1 ? W1 : blockIdx.z == 2 ? W2 : W3;
  unsigned short* T = blockIdx.z == 0 ? T0 : blockIdx.z == 1 ? T1 : blockIdx.z == 2 ? T2 : T3;
  __shared__ float tile[32][33];
  int tx = threadIdx.x & 31, ty = threadIdx.x >> 5;
  int n0 = blockIdx.x * 32, k0 = blockIdx.y * 32;
#pragma unroll
  for (int i = 0; i < 4; i++)
    tile[ty + i * 8][tx] = W[(size_t)(k0 + ty + i * 8) * 1024 + n0 + tx];
  __syncthreads();
#pragma unroll
  for (int i = 0; i < 4; i++)
    T[(size_t)(n0 + ty + i * 8) * 1024 + k0 + tx] = f2b(tile[tx][ty + i * 8]);
}

// ---------- generic 128x128 bf16 GEMM, K=1024, B given transposed [n][k] ----------
// MODE 0: out = Qh bf16 [B,H,S,64]   MODE 1: out = Kh bf16 [B,H,S,64]
// MODE 2: out = Vt bf16 [B,H,64,S]   MODE 3: out = fp32 [4096][1024]
template <int MODE>
__global__ __launch_bounds__(256, 2) void gemm_k1024(
    const unsigned short* __restrict__ A, const unsigned short* __restrict__ Bt,
    const float* __restrict__ bias, void* __restrict__ Out) {
  __shared__ unsigned short As[128 * LDA];
  __shared__ unsigned short Bs[128 * LDA];
  const int t = threadIdx.x;
  const int wid = t >> 6, lane = t & 63;
  const int lrow = lane & 15, lquad = lane >> 4;
  const int m0 = blockIdx.x * 128, n0 = blockIdx.y * 128;
  const int wm = (wid & 1) * 64, wn = (wid >> 1) * 64;
  v4f zero = {0.f, 0.f, 0.f, 0.f};
  v4f acc[4][4];
#pragma unroll
  for (int i = 0; i < 4; i++)
#pragma unroll
    for (int j = 0; j < 4; j++) acc[i][j] = zero;

  for (int kt = 0; kt < 1024; kt += 64) {
    __syncthreads();
#pragma unroll
    for (int i = 0; i < 4; i++) {           // 128 rows x 8 col-groups
      int c = t + i * 256;
      int r = c >> 3, col8 = (c & 7) * 8;
      *(v8s*)&As[r * LDA + col8] = *(const v8s*)&A[(size_t)(m0 + r) * 1024 + kt + col8];
      *(v8s*)&Bs[r * LDA + col8] = *(const v8s*)&Bt[(size_t)(n0 + r) * 1024 + kt + col8];
    }
    __syncthreads();
#pragma unroll
    for (int k32 = 0; k32 < 64; k32 += 32) {
      v8s af[4], bfv[4];
#pragma unroll
      for (int mi = 0; mi < 4; mi++)
        af[mi] = *(const v8s*)&As[(wm + mi * 16 + lrow) * LDA + k32 + lquad * 8];
#pragma unroll
      for (int ni = 0; ni < 4; ni++)
        bfv[ni] = *(const v8s*)&Bs[(wn + ni * 16 + lrow) * LDA + k32 + lquad * 8];
#pragma unroll
      for (int mi = 0; mi < 4; mi++)
#pragma unroll
        for (int ni = 0; ni < 4; ni++)
          acc[mi][ni] = __builtin_amdgcn_mfma_f32_16x16x32_bf16(af[mi], bfv[ni], acc[mi][ni], 0, 0, 0);
    }
  }
#pragma unroll
  for (int mi = 0; mi < 4; mi++) {
#pragma unroll
    for (int ni = 0; ni < 4; ni++) {
      int gn = n0 + wn + ni * 16 + lrow;
      float bv = bias[gn];
#pragma unroll
      for (int r = 0; r < 4; r++) {
        int gm = m0 + wm + mi * 16 + lquad * 4 + r;
        float val = acc[mi][ni][r] + bv;
        if (MODE == 0 || MODE == 1) {
          int b = gm >> 10, s = gm & 1023, h = gn >> 6, d = gn & 63;
          ((unsigned short*)Out)[(size_t)((b * 16 + h) * 1024 + s) * 64 + d] = f2b(val);
        } else if (MODE == 2) {
          int b = gm >> 10, s = gm & 1023, h = gn >> 6, d = gn & 63;
          ((unsigned short*)Out)[(size_t)((b * 16 + h) * 64 + d) * 1024 + s] = f2b(val);
        } else {
          ((float*)Out)[(size_t)gm * 1024 + gn] = val;
        }
      }
    }
  }
}

// ---------- logits + fused partial softmax stats ----------
// per (b,h) 1024x1024 = Qh[1024x64] @ Kh[1024x64]^T, raw fp32 -> attn.
// Also: per (row, 64-col half) masked max + expsum partials.
__global__ __launch_bounds__(256, 2) void logits_gemm_k(
    const unsigned short* __restrict__ Qh, const unsigned short* __restrict__ Kh,
    const float* __restrict__ k_mask,
    float* __restrict__ attn, float* __restrict__ part_m, float* __restrict__ part_l) {
  __shared__ unsigned short As[128 * LDA];
  __shared__ unsigned short Bs[128 * LDA];
  const int z = blockIdx.z;
  const unsigned short* A = Qh + (size_t)z * S_ * 64;
  const unsigned short* Bm = Kh + (size_t)z * S_ * 64;
  const int t = threadIdx.x;
  const int wid = t >> 6, lane = t & 63;
  const int lrow = lane & 15, lquad = lane >> 4;
  const int m0 = blockIdx.x * 128, n0 = blockIdx.y * 128;
  const int wm = (wid & 1) * 64, wn = (wid >> 1) * 64;
  v4f zero = {0.f, 0.f, 0.f, 0.f};
  v4f acc[4][4];
#pragma unroll
  for (int i = 0; i < 4; i++)
#pragma unroll
    for (int j = 0; j < 4; j++) acc[i][j] = zero;

#pragma unroll
  for (int i = 0; i < 4; i++) {
    int c = t + i * 256;
    int r = c >> 3, col8 = (c & 7) * 8;
    *(v8s*)&As[r * LDA + col8] = *(const v8s*)&A[(size_t)(m0 + r) * 64 + col8];
    *(v8s*)&Bs[r * LDA + col8] = *(const v8s*)&Bm[(size_t)(n0 + r) * 64 + col8];
  }
  __syncthreads();
#pragma unroll
  for (int k32 = 0; k32 < 64; k32 += 32) {
    v8s af[4], bfv[4];
#pragma unroll
    for (int mi = 0; mi < 4; mi++)
      af[mi] = *(const v8s*)&As[(wm + mi * 16 + lrow) * LDA + k32 + lquad * 8];
#pragma unroll
    for (int ni = 0; ni < 4; ni++)
      bfv[ni] = *(const v8s*)&Bs[(wn + ni * 16 + lrow) * LDA + k32 + lquad * 8];
#pragma unroll
    for (int mi = 0; mi < 4; mi++)
#pragma unroll
      for (int ni = 0; ni < 4; ni++)
        acc[mi][ni] = __builtin_amdgcn_mfma_f32_16x16x32_bf16(af[mi], bfv[ni], acc[mi][ni], 0, 0, 0);
  }
  // raw logits out
  float* orow = attn + (size_t)z * S_ * S_;
#pragma unroll
  for (int mi = 0; mi < 4; mi++)
#pragma unroll
    for (int ni = 0; ni < 4; ni++) {
      int gn = n0 + wn + ni * 16 + lrow;
#pragma unroll
      for (int r = 0; r < 4; r++) {
        int gm = m0 + wm + mi * 16 + lquad * 4 + r;
        orow[(size_t)gm * 1024 + gn] = acc[mi][ni][r];
      }
    }
  // fused partial softmax stats over this wave's 64-col half
  const float* km = k_mask + (z >> 4) * 1024;
  float kmv[4];
#pragma unroll
  for (int ni = 0; ni < 4; ni++) kmv[ni] = km[n0 + wn + ni * 16 + lrow];
  const int wh = wid >> 1;                       // which 64-col half (0/1) within tile
  const int pbase = (z * 16 + blockIdx.y * 2 + wh) * 1024;
#pragma unroll
  for (int mi = 0; mi < 4; mi++) {
#pragma unroll
    for (int r = 0; r < 4; r++) {
      float ml = -1e30f;
#pragma unroll
      for (int ni = 0; ni < 4; ni++) {
        float s = acc[mi][ni][r] * 0.125f;
        if (kmv[ni] != 0.f) ml = fmaxf(ml, s);
      }
#pragma unroll
      for (int off = 1; off < 16; off <<= 1) ml = fmaxf(ml, __shfl_xor(ml, off));
      float ll = 0.f;
#pragma unroll
      for (int ni = 0; ni < 4; ni++)
        if (kmv[ni] != 0.f) ll += __expf(acc[mi][ni][r] * 0.125f - ml);
#pragma unroll
      for (int off = 1; off < 16; off <<= 1) ll += __shfl_xor(ll, off);
      if (lrow == 0) {
        int grow = m0 + wm + mi * 16 + lquad * 4 + r;
        part_m[pbase + grow] = ml;
        part_l[pbase + grow] = ll;
      }
    }
  }
}

// ---------- combine 16 partials per row -> stats (max, recip) ----------
__global__ __launch_bounds__(256) void reduce_stats_k(
    const float* __restrict__ part_m, const float* __restrict__ part_l,
    const float* __restrict__ q_mask, float* __restrict__ stats) {
  const int r = blockIdx.x * 256 + threadIdx.x;  // z*1024 + q, 65536 total
  const int z = r >> 10, q = r & 1023, b = z >> 4;
  float M = -1e30f;
#pragma unroll
  for (int i = 0; i < 16; i++) M = fmaxf(M, part_m[(z * 16 + i) * 1024 + q]);
  const bool any = (M > -1e29f);
  const float MM = any ? M : 0.f;
  float L = 0.f;
#pragma unroll
  for (int i = 0; i < 16; i++) {
    float li = part_l[(z * 16 + i) * 1024 + q];
    if (li > 0.f) L += li * __expf(part_m[(z * 16 + i) * 1024 + q] - MM);
  }
  float recip = (any && q_mask[b * 1024 + q] != 0.f && L > 0.f) ? (1.f / L) : 0.f;
  stats[r] = MM;
  stats[65536 + r] = recip;
}

// ---------- context: per (b,h): C[1024x64] = P[1024x1024] @ Vt[64x1024]^T ----------
__global__ __launch_bounds__(256, 2) void context_gemm_k(
    const float* __restrict__ attn, const float* __restrict__ stats,
    const float* __restrict__ k_mask, const unsigned short* __restrict__ Vt,
    unsigned short* __restrict__ ctx) {
  __shared__ unsigned short As[256 * LDA];  // 36 KB
  __shared__ unsigned short Bs[64 * LDA];   // 9 KB
  const int z = blockIdx.z, b = z >> 4, h = z & 15;
  const int m0 = blockIdx.x * 256;
  const float* P = attn + (size_t)z * S_ * S_;
  const float* km = k_mask + b * 1024;
  const float* Ms = stats + (size_t)z * 1024;
  const float* Rs = stats + 65536 + (size_t)z * 1024;
  const int t = threadIdx.x;
  const int wid = t >> 6, lane = t & 63, lrow = lane & 15, lquad = lane >> 4;
  v4f zero = {0.f, 0.f, 0.f, 0.f};
  v4f acc[4][4];
#pragma unroll
  for (int i = 0; i < 4; i++)
#pragma unroll
    for (int j = 0; j < 4; j++) acc[i][j] = zero;

  for (int kt = 0; kt < 1024; kt += 64) {
    __syncthreads();
#pragma unroll
    for (int i = 0; i < 8; i++) {
      int c = t + i * 256;
      int r = c >> 3, col8 = (c & 7) * 8;
      int qq = m0 + r;
      float mR = Ms[qq], rR = Rs[qq];
      const v4f* s4 = (const v4f*)(P + (size_t)qq * 1024 + kt + col8);
      v4f x0 = s4[0], x1 = s4[1];
      union { unsigned short u[8]; v8s v; } o;
#pragma unroll
      for (int j = 0; j < 4; j++) {
        int kc = kt + col8 + j;
        o.u[j] = f2b(km[kc] != 0.f ? __expf(x0[j] * 0.125f - mR) * rR : 0.f);
      }
#pragma unroll
      for (int j = 0; j < 4; j++) {
        int kc = kt + col8 + 4 + j;
        o.u[4 + j] = f2b(km[kc] != 0.f ? __expf(x1[j] * 0.125f - mR) * rR : 0.f);
      }
      *(v8s*)&As[r * LDA + col8] = o.v;
    }
#pragma unroll
    for (int i = 0; i < 2; i++) {
      int c = t + i * 256;
      int r = c >> 3, col8 = (c & 7) * 8;
      *(v8s*)&Bs[r * LDA + col8] = *(const v8s*)&Vt[((size_t)z * 64 + r) * 1024 + kt + col8];
    }
    __syncthreads();
#pragma unroll
    for (int k32 = 0; k32 < 64; k32 += 32) {
      v8s af[4], bfv[4];
#pragma unroll
      for (int mi = 0; mi < 4; mi++)
        af[mi] = *(const v8s*)&As[(wid * 64 + mi * 16 + lrow) * LDA + k32 + lquad * 8];
#pragma unroll
      for (int ni = 0; ni < 4; ni++)
        bfv[ni] = *(const v8s*)&Bs[(ni * 16 + lrow) * LDA + k32 + lquad * 8];
#pragma unroll
      for (int mi = 0; mi < 4; mi++)
#pragma unroll
        for (int ni = 0; ni < 4; ni++)
          acc[mi][ni] = __builtin_amdgcn_mfma_f32_16x16x32_bf16(af[mi], bfv[ni], acc[mi][ni], 0, 0, 0);
    }
  }
#pragma unroll
  for (int mi = 0; mi < 4; mi++)
#pragma unroll
    for (int ni = 0; ni < 4; ni++) {
      int d = ni * 16 + lrow;
#pragma unroll
      for (int r = 0; r < 4; r++) {
        int s = m0 + wid * 64 + mi * 16 + lquad * 4 + r;
        ctx[(size_t)(b * 1024 + s) * 1024 + h * 64 + d] = f2b(acc[mi][ni][r]);
      }
    }
}

// ---------- residual + LayerNorm, one block per row ----------
__global__ __launch_bounds__(256) void resid_ln_k(
    const float* __restrict__ tmp, const float* __restrict__ resid,
    const float* __restrict__ gamma, const float* __restrict__ beta,
    float* __restrict__ out) {
  const int r = blockIdx.x, t = threadIdx.x;
  v4f x = *(const v4f*)(tmp + (size_t)r * 1024 + t * 4);
  v4f rv = *(const v4f*)(resid + (size_t)r * 1024 + t * 4);
  x = x + rv;
  float s = x[0] + x[1] + x[2] + x[3];
  float ss = x[0] * x[0] + x[1] * x[1] + x[2] * x[2] + x[3] * x[3];
#pragma unroll
  for (int off = 32; off; off >>= 1) { s += __shfl_xor(s, off); ss += __shfl_xor(ss, off); }
  __shared__ float red[8];
  const int wid = t >> 6, lane = t & 63;
  if (lane == 0) { red[wid] = s; red[4 + wid] = ss; }
  __syncthreads();
  s = red[0] + red[1] + red[2] + red[3];
  ss = red[4] + red[5] + red[6] + red[7];
  const float mu = s * (1.f / 1024.f);
  float var = ss * (1.f / 1024.f) - mu * mu;
  var = fmaxf(var, 0.f);
  const float rs = rsqrtf(var + 1e-5f);
  v4f g = *(const v4f*)(gamma + t * 4);
  v4f be = *(const v4f*)(beta + t * 4);
  v4f o = (x - mu) * rs * g + be;
  *(v4f*)(out + (size_t)r * 1024 + t * 4) = o;
}

extern "C" void kernel_launch(void* const* d_in, const int* in_sizes, int n_in,
                              void* d_out, int out_size, void* d_ws, size_t ws_size,
                              hipStream_t stream) {
  const float* q      = (const float*)d_in[0];
  const float* k      = (const float*)d_in[1];
  const float* v      = (const float*)d_in[2];
  const float* q_mask = (const float*)d_in[3];
  const float* k_mask = (const float*)d_in[4];
  const float* Wq = (const float*)d_in[5];
  const float* bq = (const float*)d_in[6];
  const float* Wk = (const float*)d_in[7];
  const float* bk = (const float*)d_in[8];
  const float* Wv = (const float*)d_in[9];
  const float* bv = (const float*)d_in[10];
  const float* Wf = (const float*)d_in[11];
  const float* bf = (const float*)d_in[12];
  const float* gamma = (const float*)d_in[13];
  const float* beta  = (const float*)d_in[14];

  float* out0 = (float*)d_out;
  float* attn = out0 + (size_t)MTOT * 1024;  // 64M fp32 raw logits

  char* w = (char*)d_ws;
  const size_t MB = (size_t)1 << 20;
  unsigned short* qb  = (unsigned short*)(w + 0);
  unsigned short* kb  = (unsigned short*)(w + 8 * MB);
  unsigned short* vb  = (unsigned short*)(w + 16 * MB);
  unsigned short* WqT = (unsigned short*)(w + 24 * MB);
  unsigned short* WkT = (unsigned short*)(w + 26 * MB);
  unsigned short* WvT = (unsigned short*)(w + 28 * MB);
  unsigned short* WfT = (unsigned short*)(w + 30 * MB);
  unsigned short* Qh  = (unsigned short*)(w + 32 * MB);
  unsigned short* Kh  = (unsigned short*)(w + 40 * MB);
  unsigned short* Vt  = (unsigned short*)(w + 48 * MB);
  float* stats        = (float*)(w + 56 * MB);           // 512 KB
  float* part_m       = (float*)(w + 57 * MB);           // 4 MB (64*16*1024)
  float* part_l       = (float*)(w + 61 * MB);           // 4 MB
  unsigned short* ctx = (unsigned short*)(w + 0);        // reuse qb
  float* tmp          = (float*)(w + 8 * MB);            // reuse kb+vb (16 MB)

  cast3_k<<<dim3(2048, 3), 256, 0, stream>>>(q, k, v, qb, kb, vb);
  transpose_cast_k<<<dim3(32, 32, 4), 256, 0, stream>>>(Wq, Wk, Wv, Wf, WqT, WkT, WvT, WfT);
  gemm_k1024<0><<<dim3(32, 8), 256, 0, stream>>>(qb, WqT, bq, Qh);
  gemm_k1024<1><<<dim3(32, 8), 256, 0, stream>>>(kb, WkT, bk, Kh);
  gemm_k1024<2><<<dim3(32, 8), 256, 0, stream>>>(vb, WvT, bv, Vt);
  logits_gemm_k<<<dim3(8, 8, 64), 256, 0, stream>>>(Qh, Kh, k_mask, attn, part_m, part_l);
  reduce_stats_k<<<256, 256, 0, stream>>>(part_m, part_l, q_mask, stats);
  context_gemm_k<<<dim3(4, 1, 64), 256, 0, stream>>>(attn, stats, k_mask, Vt, ctx);
  gemm_k1024<3><<<dim3(32, 8), 256, 0, stream>>>(ctx, WfT, bf, tmp);
  resid_ln_k<<<4096, 256, 0, stream>>>(tmp, v, gamma, beta, out0);
}